// Round 5
// baseline (250.110 us; speedup 1.0000x reference)
//
#include <hip/hip_runtime.h>
#include <hip/hip_bf16.h>

#define NODES_DIM 64   // H*D = 4*16
#define SL_DIM    12   // H*DC = 4*3
#define CAP       64   // bucket capacity; deg ~ Poisson(16), P(>=64) ~ 1e-18

// round-to-nearest-even fp32 -> bf16
__device__ __forceinline__ unsigned short f2bf(float f) {
    union { float f; unsigned u; } x; x.f = f;
    const unsigned r = x.u + 0x7FFFu + ((x.u >> 16) & 1u);
    return (unsigned short)(r >> 16);
}

// ---------------------------------------------------------------------------
// Kernel 1: fused QKV projection. Q fp32; K,V packed bf16 (KV = v<<16 | k).
// 8 rows/slot (32 rows/block) to keep VGPR ~110 -> 4-5 waves/SIMD.
// W in LDS (48 KB); h loads wave-uniform -> scalar loads.
// ---------------------------------------------------------------------------
__global__ __launch_bounds__(256) void qkv_kernel(
    const float* __restrict__ h,
    const float* __restrict__ Wq, const float* __restrict__ bq,
    const float* __restrict__ Wk, const float* __restrict__ bk,
    const float* __restrict__ Wv, const float* __restrict__ bv,
    float* __restrict__ Q, unsigned* __restrict__ KV,
    int N)
{
    __shared__ float sW[3][64][64];   // 48 KB

    for (int i = threadIdx.x; i < 64 * 64; i += 256) {
        sW[0][i >> 6][i & 63] = Wq[i];
        sW[1][i >> 6][i & 63] = Wk[i];
        sW[2][i >> 6][i & 63] = Wv[i];
    }
    __syncthreads();

    const int c    = threadIdx.x & 63;
    const int slot = __builtin_amdgcn_readfirstlane((int)(threadIdx.x >> 6));
    const int rowBase = blockIdx.x * 32 + slot * 8;
    if (rowBase >= N) return;
    const int nrows = (N - rowBase < 8) ? (N - rowBase) : 8;

    float acc0[8], acc1[8], acc2[8];
#pragma unroll
    for (int r = 0; r < 8; ++r) { acc0[r] = 0.f; acc1[r] = 0.f; acc2[r] = 0.f; }

    if (nrows == 8) {
        for (int k4 = 0; k4 < 16; ++k4) {
            float4 hv[8];
#pragma unroll
            for (int r = 0; r < 8; ++r)
                hv[r] = ((const float4*)(h + (size_t)(rowBase + r) * 64))[k4];
#pragma unroll
            for (int kk = 0; kk < 4; ++kk) {
                const int k = k4 * 4 + kk;
                const float wq = sW[0][k][c];
                const float wk = sW[1][k][c];
                const float wv = sW[2][k][c];
#pragma unroll
                for (int r = 0; r < 8; ++r) {
                    const float hh = (&hv[r].x)[kk];
                    acc0[r] += hh * wq;
                    acc1[r] += hh * wk;
                    acc2[r] += hh * wv;
                }
            }
        }
    } else {
        for (int k4 = 0; k4 < 16; ++k4) {
            float4 hv[8];
#pragma unroll
            for (int r = 0; r < 8; ++r)
                hv[r] = (r < nrows)
                    ? ((const float4*)(h + (size_t)(rowBase + r) * 64))[k4]
                    : make_float4(0.f, 0.f, 0.f, 0.f);
#pragma unroll
            for (int kk = 0; kk < 4; ++kk) {
                const int k = k4 * 4 + kk;
                const float wq = sW[0][k][c];
                const float wk = sW[1][k][c];
                const float wv = sW[2][k][c];
#pragma unroll
                for (int r = 0; r < 8; ++r) {
                    const float hh = (&hv[r].x)[kk];
                    acc0[r] += hh * wq;
                    acc1[r] += hh * wk;
                    acc2[r] += hh * wv;
                }
            }
        }
    }

    const float bqc = bq[c], bkc = bk[c], bvc = bv[c];
#pragma unroll
    for (int r = 0; r < 8; ++r) {
        if (r < nrows) {
            const size_t o = (size_t)(rowBase + r) * 64 + c;
            Q[o] = acc0[r] + bqc;
            const unsigned short kb = f2bf(acc1[r] + bkc);
            const unsigned short vb = f2bf(acc2[r] + bvc);
            KV[o] = ((unsigned)vb << 16) | (unsigned)kb;
        }
    }
}

// ---------------------------------------------------------------------------
// Bucket fill: one atomic + one store per edge.
// ---------------------------------------------------------------------------
__global__ __launch_bounds__(256) void fill_kernel(
    const int* __restrict__ src, const int* __restrict__ dst,
    int* __restrict__ cursor, int* __restrict__ list, int E)
{
    const int e = blockIdx.x * 256 + threadIdx.x;
    if (e < E) {
        const int dv  = dst[e];
        const int pos = atomicAdd(&cursor[dv], 1);
        if (pos < CAP) list[((size_t)dv << 6) + pos] = src[e];
    }
}

// ---------------------------------------------------------------------------
// Node phase. One wave per node; lane = (e in 0..15, p in 0..3): edge-slot e,
// dim-quad p. 16-edge chunks: 4x dwordx4 KV gather (contig 64 B per src),
// in-lane partial dots per head, ONE 2-stage p-reduce per chunk, exp per
// (edge,head) once, V accumulated in-lane. Epilogue: 4-stage halving
// transpose-reduce lands lane on out-dim; zsum allreduce rides along.
// No per-edge cross-lane ops, no fp32 atomics.
// ---------------------------------------------------------------------------
__global__ __launch_bounds__(256) void node_kernel(
    const float* __restrict__ Q, const unsigned* __restrict__ KV,
    const float* __restrict__ s_l,
    const int* __restrict__ cursor, const int* __restrict__ list,
    float* __restrict__ out, int N)
{
    const int t = blockIdx.x * 256 + threadIdx.x;
    const int node = t >> 6;
    if (node >= N) return;
    const int lane = threadIdx.x & 63;
    const int e = lane & 15;
    const int p = lane >> 4;

    int deg = cursor[node];
    deg = (deg > CAP) ? CAP : deg;

    // q[i*4+t] = Q[node][16i + 4p + t]  (this lane's 16 dims, 4 per head)
    float q[16];
    {
        const float* qb = Q + (size_t)node * 64 + (p << 2);
#pragma unroll
        for (int i = 0; i < 4; ++i) {
            const float4 f = *(const float4*)(qb + (i << 4));
            q[i*4+0] = f.x; q[i*4+1] = f.y; q[i*4+2] = f.z; q[i*4+3] = f.w;
        }
    }
    // slv[h] = s_l[node][h*3 + p]  (component p of head h; p==3 inert)
    float slv[4];
    {
        const float* sb = s_l + (size_t)node * SL_DIM + p;
#pragma unroll
        for (int hh = 0; hh < 4; ++hh)
            slv[hh] = (p < 3) ? sb[hh * 3] : 0.f;
    }

    float accV[16];
#pragma unroll
    for (int j = 0; j < 16; ++j) accV[j] = 0.f;
    float zs[4] = {0.f, 0.f, 0.f, 0.f};

    const int nch = (deg + 15) >> 4;
    for (int c = 0; c < nch; ++c) {
        const int off = (c << 4) + e;
        const bool valid = off < deg;
        const int loff = valid ? off : 0;          // clamp: avoid poisoned slots
        const int sidx = list[((size_t)node << 6) + loff];

        unsigned kv[16];
        {
            const unsigned* kb = KV + (size_t)sidx * 64 + (p << 2);
#pragma unroll
            for (int i = 0; i < 4; ++i) {
                const uint4 u = *(const uint4*)(kb + (i << 4));
                kv[i*4+0] = u.x; kv[i*4+1] = u.y; kv[i*4+2] = u.z; kv[i*4+3] = u.w;
            }
        }

        float pd[4], pds[4];
        {
            const float* sb = s_l + (size_t)sidx * SL_DIM + p;
#pragma unroll
            for (int hh = 0; hh < 4; ++hh) {
                const float a  = (p < 3) ? sb[hh * 3] : 0.f;
                const float df = a - slv[hh];
                pds[hh] = df * df;
                float s = 0.f;
#pragma unroll
                for (int tt = 0; tt < 4; ++tt) {
                    const int j = hh * 4 + tt;
                    s += q[j] * __uint_as_float(kv[j] << 16);
                }
                pd[hh] = s;
            }
        }

        // reduce over the p dimension (lane bits 4..5): 2-stage butterfly
#pragma unroll
        for (int m = 16; m <= 32; m <<= 1) {
#pragma unroll
            for (int hh = 0; hh < 4; ++hh) {
                pd[hh]  += __shfl_xor(pd[hh],  m);
                pds[hh] += __shfl_xor(pds[hh], m);
            }
        }

        float news[4];
#pragma unroll
        for (int hh = 0; hh < 4; ++hh) {
            const float sc    = fminf(fmaxf(pd[hh] * 0.25f, -5.f), 5.f);
            const float score = __expf(sc);
            const float w     = __expf(-pds[hh] * pds[hh]);
            news[hh] = valid ? (score * w) : 0.f;
            zs[hh]  += valid ? score : 0.f;
        }

#pragma unroll
        for (int j = 0; j < 16; ++j)
            accV[j] += news[j >> 2] * __uint_as_float(kv[j] & 0xFFFF0000u);
    }

    // zsum allreduce over the 16 e-lanes (bits 0..3)
#pragma unroll
    for (int m = 1; m <= 8; m <<= 1) {
#pragma unroll
        for (int hh = 0; hh < 4; ++hh)
            zs[hh] += __shfl_xor(zs[hh], m);
    }

    // halving transpose-reduce of accV over e-lanes; lane ends with j == e
#pragma unroll
    for (int bit = 8; bit >= 1; bit >>= 1) {
        const bool hi = (e & bit) != 0;
#pragma unroll
        for (int j = 0; j < 8; ++j) {
            if (j < bit) {
                const float keep = hi ? accV[j + bit] : accV[j];
                const float send = hi ? accV[j]       : accV[j + bit];
                accV[j] = keep + __shfl_xor(send, bit);
            }
        }
    }

    // lane's final value = dim 16*(e>>2) + 4p + (e&3); its head = e>>2
    const float za = (e & 4) ? zs[1] : zs[0];
    const float zb = (e & 4) ? zs[3] : zs[2];
    const float zf = (e & 8) ? zb : za;

    const int dim = ((e >> 2) << 4) + (p << 2) + (e & 3);
    const float r = accV[0];
    out[(size_t)node * 64 + dim] = (zf > 0.f) ? (r / zf) : r;
}

extern "C" void kernel_launch(void* const* d_in, const int* in_sizes, int n_in,
                              void* d_out, int out_size, void* d_ws, size_t ws_size,
                              hipStream_t stream) {
    const float* h   = (const float*)d_in[0];
    const float* s_l = (const float*)d_in[1];
    const float* Wq  = (const float*)d_in[2];
    const float* bq  = (const float*)d_in[3];
    const float* Wk  = (const float*)d_in[4];
    const float* bk  = (const float*)d_in[5];
    const float* Wv  = (const float*)d_in[6];
    const float* bv  = (const float*)d_in[7];
    const int*   src = (const int*)d_in[8];
    const int*   dst = (const int*)d_in[9];
    float* out = (float*)d_out;

    const int N = in_sizes[0] / 64;   // 50000
    const int E = in_sizes[8];        // 800000

    // workspace: Q fp32 (N*64) | KV packed (N*64) | cursor (N) | list (N*CAP)
    float*    Q      = (float*)d_ws;
    unsigned* KV     = (unsigned*)(Q + (size_t)N * NODES_DIM);
    int*      cursor = (int*)(KV + (size_t)N * NODES_DIM);
    int*      list   = cursor + N;

    hipMemsetAsync(cursor, 0, (size_t)N * sizeof(int), stream);

    qkv_kernel<<<(N + 31) / 32, 256, 0, stream>>>(
        h, Wq, bq, Wk, bk, Wv, bv, Q, KV, N);

    fill_kernel<<<(E + 255) / 256, 256, 0, stream>>>(src, dst, cursor, list, E);

    const long long nthreads = (long long)N * 64;
    node_kernel<<<(int)((nthreads + 255) / 256), 256, 0, stream>>>(
        Q, KV, s_l, cursor, list, out, N);
}

// Round 6
// 200.619 us; speedup vs baseline: 1.2467x; 1.2467x over previous
//
#include <hip/hip_runtime.h>
#include <hip/hip_bf16.h>

#define NODES_DIM 64   // H*D = 4*16
#define SL_DIM    12   // H*DC = 4*3
#define CAP       64   // bucket capacity; deg ~ Poisson(16), P(>=64) ~ 1e-18

// round-to-nearest-even fp32 -> bf16
__device__ __forceinline__ unsigned short f2bf(float f) {
    union { float f; unsigned u; } x; x.f = f;
    const unsigned r = x.u + 0x7FFFu + ((x.u >> 16) & 1u);
    return (unsigned short)(r >> 16);
}

// ---------------------------------------------------------------------------
// Kernel 1: fused QKV projection. Q fp32; K,V packed bf16 (KV = v<<16 | k).
// 8 rows/slot (32 rows/block). W in LDS (48 KB); h loads wave-uniform ->
// scalar loads.
// ---------------------------------------------------------------------------
__global__ __launch_bounds__(256) void qkv_kernel(
    const float* __restrict__ h,
    const float* __restrict__ Wq, const float* __restrict__ bq,
    const float* __restrict__ Wk, const float* __restrict__ bk,
    const float* __restrict__ Wv, const float* __restrict__ bv,
    float* __restrict__ Q, unsigned* __restrict__ KV,
    int N)
{
    __shared__ float sW[3][64][64];   // 48 KB

    for (int i = threadIdx.x; i < 64 * 64; i += 256) {
        sW[0][i >> 6][i & 63] = Wq[i];
        sW[1][i >> 6][i & 63] = Wk[i];
        sW[2][i >> 6][i & 63] = Wv[i];
    }
    __syncthreads();

    const int c    = threadIdx.x & 63;
    const int slot = __builtin_amdgcn_readfirstlane((int)(threadIdx.x >> 6));
    const int rowBase = blockIdx.x * 32 + slot * 8;
    if (rowBase >= N) return;
    const int nrows = (N - rowBase < 8) ? (N - rowBase) : 8;

    float acc0[8], acc1[8], acc2[8];
#pragma unroll
    for (int r = 0; r < 8; ++r) { acc0[r] = 0.f; acc1[r] = 0.f; acc2[r] = 0.f; }

    if (nrows == 8) {
        for (int k4 = 0; k4 < 16; ++k4) {
            float4 hv[8];
#pragma unroll
            for (int r = 0; r < 8; ++r)
                hv[r] = ((const float4*)(h + (size_t)(rowBase + r) * 64))[k4];
#pragma unroll
            for (int kk = 0; kk < 4; ++kk) {
                const int k = k4 * 4 + kk;
                const float wq = sW[0][k][c];
                const float wk = sW[1][k][c];
                const float wv = sW[2][k][c];
#pragma unroll
                for (int r = 0; r < 8; ++r) {
                    const float hh = (&hv[r].x)[kk];
                    acc0[r] += hh * wq;
                    acc1[r] += hh * wk;
                    acc2[r] += hh * wv;
                }
            }
        }
    } else {
        for (int k4 = 0; k4 < 16; ++k4) {
            float4 hv[8];
#pragma unroll
            for (int r = 0; r < 8; ++r)
                hv[r] = (r < nrows)
                    ? ((const float4*)(h + (size_t)(rowBase + r) * 64))[k4]
                    : make_float4(0.f, 0.f, 0.f, 0.f);
#pragma unroll
            for (int kk = 0; kk < 4; ++kk) {
                const int k = k4 * 4 + kk;
                const float wq = sW[0][k][c];
                const float wk = sW[1][k][c];
                const float wv = sW[2][k][c];
#pragma unroll
                for (int r = 0; r < 8; ++r) {
                    const float hh = (&hv[r].x)[kk];
                    acc0[r] += hh * wq;
                    acc1[r] += hh * wk;
                    acc2[r] += hh * wv;
                }
            }
        }
    }

    const float bqc = bq[c], bkc = bk[c], bvc = bv[c];
#pragma unroll
    for (int r = 0; r < 8; ++r) {
        if (r < nrows) {
            const size_t o = (size_t)(rowBase + r) * 64 + c;
            Q[o] = acc0[r] + bqc;
            const unsigned short kb = f2bf(acc1[r] + bkc);
            const unsigned short vb = f2bf(acc2[r] + bvc);
            KV[o] = ((unsigned)vb << 16) | (unsigned)kb;
        }
    }
}

// ---------------------------------------------------------------------------
// Bucket fill: one atomic + one store per edge.
// ---------------------------------------------------------------------------
__global__ __launch_bounds__(256) void fill_kernel(
    const int* __restrict__ src, const int* __restrict__ dst,
    int* __restrict__ cursor, int* __restrict__ list, int E)
{
    const int e = blockIdx.x * 256 + threadIdx.x;
    if (e < E) {
        const int dv  = dst[e];
        const int pos = atomicAdd(&cursor[dv], 1);
        if (pos < CAP) list[((size_t)dv << 6) + pos] = src[e];
    }
}

// ---------------------------------------------------------------------------
// Node phase, edge-quad layout. One wave per node.
// lane = e2*16 + head*4 + quad: edge-subset e2 (4 edges/group), head, and a
// 4-dim quad of that head. Per 4-edge group: 1 dwordx4 KV load per lane
// (256 B contiguous per source), 4-FMA partial dot, width-4 2-stage shfl
// reduce for dot and dij, exp amortized (2 per lane per 4 edges), V
// accumulated in-lane. Epilogue: 2-stage e2-reduce + masked dwordx4 store.
// ---------------------------------------------------------------------------
__global__ __launch_bounds__(256) void node_kernel(
    const float* __restrict__ Q, const unsigned* __restrict__ KV,
    const float* __restrict__ s_l,
    const int* __restrict__ cursor, const int* __restrict__ list,
    float* __restrict__ out, int N)
{
    const int t = blockIdx.x * 256 + threadIdx.x;
    const int node = t >> 6;
    if (node >= N) return;
    const int lane = threadIdx.x & 63;
    const int e2   = lane >> 4;       // 0..3  edge sub-slot
    const int hq   = lane & 15;       // head*4 + quad
    const int head = hq >> 2;
    const int quad = hq & 3;

    int deg = cursor[node];
    deg = (deg > CAP) ? CAP : deg;

    const float4 qv = *(const float4*)(Q + (size_t)node * 64 + (hq << 2));
    const float slv = (quad < 3) ? s_l[(size_t)node * SL_DIM + head * 3 + quad] : 0.f;

    const int* lbase = list + ((size_t)node << 6);

    float4 accV = make_float4(0.f, 0.f, 0.f, 0.f);
    float zs = 0.f;

    const int ng = (deg + 3) >> 2;
#pragma unroll 2
    for (int i = 0; i < ng; ++i) {
        const int slot  = (i << 2) + e2;
        const bool valid = slot < deg;
        const int sidx  = lbase[valid ? slot : 0];

        const uint4 kv = *(const uint4*)(KV + (size_t)sidx * 64 + (hq << 2));
        const float a  = (quad < 3) ? s_l[(size_t)sidx * SL_DIM + head * 3 + quad] : 0.f;

        float dt = __uint_as_float(kv.x << 16) * qv.x
                 + __uint_as_float(kv.y << 16) * qv.y
                 + __uint_as_float(kv.z << 16) * qv.z
                 + __uint_as_float(kv.w << 16) * qv.w;
        const float df = a - slv;
        float ds = df * df;

        dt += __shfl_xor(dt, 1, 4);
        dt += __shfl_xor(dt, 2, 4);
        ds += __shfl_xor(ds, 1, 4);
        ds += __shfl_xor(ds, 2, 4);

        const float sc = fminf(fmaxf(dt * 0.25f, -5.f), 5.f);
        float score = __expf(sc);
        score = valid ? score : 0.f;
        const float w    = __expf(-ds * ds);
        const float news = score * w;
        zs += score;

        accV.x += __uint_as_float(kv.x & 0xFFFF0000u) * news;
        accV.y += __uint_as_float(kv.y & 0xFFFF0000u) * news;
        accV.z += __uint_as_float(kv.z & 0xFFFF0000u) * news;
        accV.w += __uint_as_float(kv.w & 0xFFFF0000u) * news;
    }

    // reduce across the 4 e2 groups (lane bits 4,5)
#pragma unroll
    for (int m = 16; m <= 32; m <<= 1) {
        accV.x += __shfl_xor(accV.x, m);
        accV.y += __shfl_xor(accV.y, m);
        accV.z += __shfl_xor(accV.z, m);
        accV.w += __shfl_xor(accV.w, m);
        zs     += __shfl_xor(zs, m);
    }

    if (e2 == 0) {
        const float inv = (zs > 0.f) ? (1.f / zs) : 1.f;
        float4 o;
        o.x = accV.x * inv; o.y = accV.y * inv;
        o.z = accV.z * inv; o.w = accV.w * inv;
        *(float4*)(out + (size_t)node * 64 + (hq << 2)) = o;
    }
}

extern "C" void kernel_launch(void* const* d_in, const int* in_sizes, int n_in,
                              void* d_out, int out_size, void* d_ws, size_t ws_size,
                              hipStream_t stream) {
    const float* h   = (const float*)d_in[0];
    const float* s_l = (const float*)d_in[1];
    const float* Wq  = (const float*)d_in[2];
    const float* bq  = (const float*)d_in[3];
    const float* Wk  = (const float*)d_in[4];
    const float* bk  = (const float*)d_in[5];
    const float* Wv  = (const float*)d_in[6];
    const float* bv  = (const float*)d_in[7];
    const int*   src = (const int*)d_in[8];
    const int*   dst = (const int*)d_in[9];
    float* out = (float*)d_out;

    const int N = in_sizes[0] / 64;   // 50000
    const int E = in_sizes[8];        // 800000

    // workspace: Q fp32 (N*64) | KV packed (N*64) | cursor (N) | list (N*CAP)
    float*    Q      = (float*)d_ws;
    unsigned* KV     = (unsigned*)(Q + (size_t)N * NODES_DIM);
    int*      cursor = (int*)(KV + (size_t)N * NODES_DIM);
    int*      list   = cursor + N;

    hipMemsetAsync(cursor, 0, (size_t)N * sizeof(int), stream);

    qkv_kernel<<<(N + 31) / 32, 256, 0, stream>>>(
        h, Wq, bq, Wk, bk, Wv, bv, Q, KV, N);

    fill_kernel<<<(E + 255) / 256, 256, 0, stream>>>(src, dst, cursor, list, E);

    const long long nthreads = (long long)N * 64;
    node_kernel<<<(int)((nthreads + 255) / 256), 256, 0, stream>>>(
        Q, KV, s_l, cursor, list, out, N);
}

// Round 7
// 172.825 us; speedup vs baseline: 1.4472x; 1.1608x over previous
//
#include <hip/hip_runtime.h>
#include <hip/hip_bf16.h>

#define NODES_DIM 64   // H*D = 4*16
#define SL_DIM    12   // H*DC = 4*3
#define CAP       64   // bucket capacity; deg ~ Poisson(16), P(>=64) ~ 1e-18

// round-to-nearest-even fp32 -> bf16
__device__ __forceinline__ unsigned short f2bf(float f) {
    union { float f; unsigned u; } x; x.f = f;
    const unsigned r = x.u + 0x7FFFu + ((x.u >> 16) & 1u);
    return (unsigned short)(r >> 16);
}

// ---------------------------------------------------------------------------
// Fused kernel: heterogeneous grid. Role by blockIdx%3: r in {0,1} -> QKV
// block (VALU/LDS-bound), r==2 -> edge-bucket fill block (atomic/latency-
// bound, ~0 VALU). The two roles have no data dependence and use disjoint
// pipes, so co-residency on a CU overlaps them at ~max() instead of sum().
//
// QKV path: Q fp32; K,V packed bf16 (KV = v<<16 | k). 8 rows/slot (32/block).
// W in LDS (48 KB); h loads wave-uniform -> scalar loads.
// Fill path: 1024 edges/block, 4 per thread (stride-256 coalesced loads),
// 4 independent atomic+store chains per thread for memory-level parallelism.
// ---------------------------------------------------------------------------
__global__ __launch_bounds__(256) void qkv_fill_kernel(
    const float* __restrict__ h,
    const float* __restrict__ Wq, const float* __restrict__ bq,
    const float* __restrict__ Wk, const float* __restrict__ bk,
    const float* __restrict__ Wv, const float* __restrict__ bv,
    float* __restrict__ Q, unsigned* __restrict__ KV, int N,
    const int* __restrict__ src, const int* __restrict__ dst,
    int* __restrict__ cursor, int* __restrict__ list, int E)
{
    __shared__ float sW[3][64][64];   // 48 KB (qkv role only)

    const int r = blockIdx.x % 3;
    const int g = blockIdx.x / 3;

    if (r == 2) {
        // ---------------- fill role ----------------
        const int e0 = g * 1024 + threadIdx.x;
        int sv[4], dv[4];
        bool ok[4];
#pragma unroll
        for (int j = 0; j < 4; ++j) {
            const int e = e0 + j * 256;
            ok[j] = e < E;
            sv[j] = ok[j] ? src[e] : 0;
            dv[j] = ok[j] ? dst[e] : 0;
        }
#pragma unroll
        for (int j = 0; j < 4; ++j) {
            if (ok[j]) {
                const int pos = atomicAdd(&cursor[dv[j]], 1);
                if (pos < CAP) list[((size_t)dv[j] << 6) + pos] = sv[j];
            }
        }
        return;
    }

    // ---------------- qkv role ----------------
    const int qb = g * 2 + r;
    const int rowBase0 = qb * 32;
    if (rowBase0 >= N) return;

    for (int i = threadIdx.x; i < 64 * 64; i += 256) {
        sW[0][i >> 6][i & 63] = Wq[i];
        sW[1][i >> 6][i & 63] = Wk[i];
        sW[2][i >> 6][i & 63] = Wv[i];
    }
    __syncthreads();

    const int c    = threadIdx.x & 63;
    const int slot = __builtin_amdgcn_readfirstlane((int)(threadIdx.x >> 6));
    const int rowBase = rowBase0 + slot * 8;
    if (rowBase >= N) return;
    const int nrows = (N - rowBase < 8) ? (N - rowBase) : 8;

    float acc0[8], acc1[8], acc2[8];
#pragma unroll
    for (int rr = 0; rr < 8; ++rr) { acc0[rr] = 0.f; acc1[rr] = 0.f; acc2[rr] = 0.f; }

    if (nrows == 8) {
        for (int k4 = 0; k4 < 16; ++k4) {
            float4 hv[8];
#pragma unroll
            for (int rr = 0; rr < 8; ++rr)
                hv[rr] = ((const float4*)(h + (size_t)(rowBase + rr) * 64))[k4];
#pragma unroll
            for (int kk = 0; kk < 4; ++kk) {
                const int k = k4 * 4 + kk;
                const float wq = sW[0][k][c];
                const float wk = sW[1][k][c];
                const float wv = sW[2][k][c];
#pragma unroll
                for (int rr = 0; rr < 8; ++rr) {
                    const float hh = (&hv[rr].x)[kk];
                    acc0[rr] += hh * wq;
                    acc1[rr] += hh * wk;
                    acc2[rr] += hh * wv;
                }
            }
        }
    } else {
        for (int k4 = 0; k4 < 16; ++k4) {
            float4 hv[8];
#pragma unroll
            for (int rr = 0; rr < 8; ++rr)
                hv[rr] = (rr < nrows)
                    ? ((const float4*)(h + (size_t)(rowBase + rr) * 64))[k4]
                    : make_float4(0.f, 0.f, 0.f, 0.f);
#pragma unroll
            for (int kk = 0; kk < 4; ++kk) {
                const int k = k4 * 4 + kk;
                const float wq = sW[0][k][c];
                const float wk = sW[1][k][c];
                const float wv = sW[2][k][c];
#pragma unroll
                for (int rr = 0; rr < 8; ++rr) {
                    const float hh = (&hv[rr].x)[kk];
                    acc0[rr] += hh * wq;
                    acc1[rr] += hh * wk;
                    acc2[rr] += hh * wv;
                }
            }
        }
    }

    const float bqc = bq[c], bkc = bk[c], bvc = bv[c];
#pragma unroll
    for (int rr = 0; rr < 8; ++rr) {
        if (rr < nrows) {
            const size_t o = (size_t)(rowBase + rr) * 64 + c;
            Q[o] = acc0[rr] + bqc;
            const unsigned short kb = f2bf(acc1[rr] + bkc);
            const unsigned short vb = f2bf(acc2[rr] + bvc);
            KV[o] = ((unsigned)vb << 16) | (unsigned)kb;
        }
    }
}

// ---------------------------------------------------------------------------
// Node phase, edge-quad layout (unchanged from R6). One wave per node.
// lane = e2*16 + head*4 + quad. Per 4-edge group: 1 dwordx4 KV load/lane,
// width-4 2-stage shfl reduce, exp amortized, V accumulated in-lane.
// ---------------------------------------------------------------------------
__global__ __launch_bounds__(256) void node_kernel(
    const float* __restrict__ Q, const unsigned* __restrict__ KV,
    const float* __restrict__ s_l,
    const int* __restrict__ cursor, const int* __restrict__ list,
    float* __restrict__ out, int N)
{
    const int t = blockIdx.x * 256 + threadIdx.x;
    const int node = t >> 6;
    if (node >= N) return;
    const int lane = threadIdx.x & 63;
    const int e2   = lane >> 4;
    const int hq   = lane & 15;
    const int head = hq >> 2;
    const int quad = hq & 3;

    int deg = cursor[node];
    deg = (deg > CAP) ? CAP : deg;

    const float4 qv = *(const float4*)(Q + (size_t)node * 64 + (hq << 2));
    const float slv = (quad < 3) ? s_l[(size_t)node * SL_DIM + head * 3 + quad] : 0.f;

    const int* lbase = list + ((size_t)node << 6);

    float4 accV = make_float4(0.f, 0.f, 0.f, 0.f);
    float zs = 0.f;

    const int ng = (deg + 3) >> 2;
#pragma unroll 2
    for (int i = 0; i < ng; ++i) {
        const int slot  = (i << 2) + e2;
        const bool valid = slot < deg;
        const int sidx  = lbase[valid ? slot : 0];

        const uint4 kv = *(const uint4*)(KV + (size_t)sidx * 64 + (hq << 2));
        const float a  = (quad < 3) ? s_l[(size_t)sidx * SL_DIM + head * 3 + quad] : 0.f;

        float dt = __uint_as_float(kv.x << 16) * qv.x
                 + __uint_as_float(kv.y << 16) * qv.y
                 + __uint_as_float(kv.z << 16) * qv.z
                 + __uint_as_float(kv.w << 16) * qv.w;
        const float df = a - slv;
        float ds = df * df;

        dt += __shfl_xor(dt, 1, 4);
        dt += __shfl_xor(dt, 2, 4);
        ds += __shfl_xor(ds, 1, 4);
        ds += __shfl_xor(ds, 2, 4);

        const float sc = fminf(fmaxf(dt * 0.25f, -5.f), 5.f);
        float score = __expf(sc);
        score = valid ? score : 0.f;
        const float w    = __expf(-ds * ds);
        const float news = score * w;
        zs += score;

        accV.x += __uint_as_float(kv.x & 0xFFFF0000u) * news;
        accV.y += __uint_as_float(kv.y & 0xFFFF0000u) * news;
        accV.z += __uint_as_float(kv.z & 0xFFFF0000u) * news;
        accV.w += __uint_as_float(kv.w & 0xFFFF0000u) * news;
    }

#pragma unroll
    for (int m = 16; m <= 32; m <<= 1) {
        accV.x += __shfl_xor(accV.x, m);
        accV.y += __shfl_xor(accV.y, m);
        accV.z += __shfl_xor(accV.z, m);
        accV.w += __shfl_xor(accV.w, m);
        zs     += __shfl_xor(zs, m);
    }

    if (e2 == 0) {
        const float inv = (zs > 0.f) ? (1.f / zs) : 1.f;
        float4 o;
        o.x = accV.x * inv; o.y = accV.y * inv;
        o.z = accV.z * inv; o.w = accV.w * inv;
        *(float4*)(out + (size_t)node * 64 + (hq << 2)) = o;
    }
}

extern "C" void kernel_launch(void* const* d_in, const int* in_sizes, int n_in,
                              void* d_out, int out_size, void* d_ws, size_t ws_size,
                              hipStream_t stream) {
    const float* h   = (const float*)d_in[0];
    const float* s_l = (const float*)d_in[1];
    const float* Wq  = (const float*)d_in[2];
    const float* bq  = (const float*)d_in[3];
    const float* Wk  = (const float*)d_in[4];
    const float* bk  = (const float*)d_in[5];
    const float* Wv  = (const float*)d_in[6];
    const float* bv  = (const float*)d_in[7];
    const int*   src = (const int*)d_in[8];
    const int*   dst = (const int*)d_in[9];
    float* out = (float*)d_out;

    const int N = in_sizes[0] / 64;   // 50000
    const int E = in_sizes[8];        // 800000

    // workspace: Q fp32 (N*64) | KV packed (N*64) | cursor (N) | list (N*CAP)
    float*    Q      = (float*)d_ws;
    unsigned* KV     = (unsigned*)(Q + (size_t)N * NODES_DIM);
    int*      cursor = (int*)(KV + (size_t)N * NODES_DIM);
    int*      list   = cursor + N;

    hipMemsetAsync(cursor, 0, (size_t)N * sizeof(int), stream);

    // heterogeneous grid: 2/3 qkv blocks (32 rows each), 1/3 fill blocks
    const int qbc = (N + 31) / 32;            // 1563
    const int fbc = (E + 1023) / 1024;        // 782
    const int g3  = ((qbc + 1) / 2 > fbc) ? (qbc + 1) / 2 : fbc;
    qkv_fill_kernel<<<3 * g3, 256, 0, stream>>>(
        h, Wq, bq, Wk, bk, Wv, bv, Q, KV, N,
        src, dst, cursor, list, E);

    const long long nthreads = (long long)N * 64;
    node_kernel<<<(int)((nthreads + 255) / 256), 256, 0, stream>>>(
        Q, KV, s_l, cursor, list, out, N);
}